// Round 5
// baseline (196.090 us; speedup 1.0000x reference)
//
#include <hip/hip_runtime.h>
#include <stdint.h>

typedef unsigned short u16;
typedef __attribute__((ext_vector_type(8))) short bf16x8;   // 8 bf16 = 4 VGPRs
typedef bf16x8 __attribute__((may_alias)) bf16x8_a;
typedef __attribute__((ext_vector_type(4))) float f32x4;
typedef f32x4 __attribute__((may_alias)) f32x4_a;
typedef __attribute__((ext_vector_type(4))) uint32_t u32x4;

#define GLOBAL_AS __attribute__((address_space(1)))
#define LDS_AS    __attribute__((address_space(3)))

#define NB 2
#define NT 2048
#define ND 1024
#define NH 16
#define NHD 64
#define SCALE_LOG2E 0.1803368801111f   // (1/sqrt(64)) * log2(e)

static __device__ __forceinline__ u16 f2b(float f) {  // fp32 -> bf16 RNE
  uint32_t x = __builtin_bit_cast(uint32_t, f);
  x += 0x7fffu + ((x >> 16) & 1u);
  return (u16)(x >> 16);
}
// pack two fp32 -> two bf16 (truncation), one v_perm_b32
static __device__ __forceinline__ uint32_t pack2_tr(float lo, float hi) {
  return __builtin_amdgcn_perm(__builtin_bit_cast(uint32_t, hi),
                               __builtin_bit_cast(uint32_t, lo), 0x07060302u);
}

// 16B global->LDS DMA; LDS dest = wave-uniform base + lane*16 (m97/m104)
static __device__ __forceinline__ void async16(const u16* g, u16* l) {
  __builtin_amdgcn_global_load_lds((const GLOBAL_AS uint32_t*)g, (LDS_AS uint32_t*)l, 16, 0, 0);
}

// ---------------- fused fp32 -> bf16 convert for x, w_qkv, w_out (one launch) ---------
#define XN8   524288   // 4,194,304 / 8
#define WQN8  393216   // 3,145,728 / 8
__global__ __launch_bounds__(256)
void cvt_all(const float* __restrict__ x, const float* __restrict__ wq,
             const float* __restrict__ wo, u16* __restrict__ xb,
             u16* __restrict__ wqb, u16* __restrict__ wob) {
  int i = blockIdx.x * blockDim.x + threadIdx.x;
  const float* src;
  u16* dst;
  if (i < XN8)              { src = x;  dst = xb; }
  else if (i < XN8 + WQN8)  { src = wq; dst = wqb; i -= XN8; }
  else                      { src = wo; dst = wob; i -= XN8 + WQN8; }
  const f32x4 a = ((const f32x4_a*)src)[2 * i];
  const f32x4 b = ((const f32x4_a*)src)[2 * i + 1];
  bf16x8 o;
#pragma unroll
  for (int e = 0; e < 4; ++e) {
    ((short*)&o)[e]     = (short)f2b(a[e]);
    ((short*)&o)[e + 4] = (short)f2b(b[e]);
  }
  ((bf16x8_a*)dst)[i] = o;
}

// ---------------- QKV GEMM (m97 + swizzle): C = A(M,K)*W(N,K)^T + bias, K=1024 --------
// 128x128 tile, BK=64, global_load_lds staging, rotation swizzle (slot=(chunk+row)&7).
// Q block (n<1024): values pre-scaled by SCALE_LOG2E (attn then does exp2(s) directly).
// Q,K blocks: scatter [s][(b*NH+h)*NT+t][hd].
// V blocks (col0>=2048): swapped MFMA -> C^T; V^T store [bh*NHD+hd][tP] where tP is a
//   key-permutation within each 64-block: p = (k&32)|((k&12)<<1)|((k&16)>>2)|(k&3),
//   chosen so attn's PV B-fragment (keys 32ks+16(e>>2)+4quad+(e&3)) is one b128 read.
__global__ __launch_bounds__(256, 2)
void gemm_qkv(const u16* __restrict__ A, const u16* __restrict__ W,
              const float* __restrict__ bias, u16* __restrict__ C) {
  constexpr int K = 1024;
  __shared__ alignas(16) u16 As[128 * 64];
  __shared__ alignas(16) u16 Bs[128 * 64];

  const int tid  = threadIdx.x;
  const int lane = tid & 63;
  const int wave = tid >> 6;
  const int l16  = lane & 15;
  const int quad = lane >> 4;
  const int row0 = blockIdx.x * 128;
  const int col0 = blockIdx.y * 128;
  const int wm   = (wave >> 1) * 64;
  const int wn   = (wave & 1) * 64;
  const bool vblk = (col0 >= 2048);            // block-uniform

  const f32x4 z4 = {0.f, 0.f, 0.f, 0.f};
  f32x4 acc[4][4];
#pragma unroll
  for (int i = 0; i < 4; ++i)
#pragma unroll
    for (int j = 0; j < 4; ++j) acc[i][j] = z4;

  for (int k0 = 0; k0 < K; k0 += 64) {
    __syncthreads();
#pragma unroll
    for (int t = 0; t < 4; ++t) {
      const int cbase = wave * 64 + t * 256;
      const int L   = cbase + lane;
      const int row = L >> 3;
      const int h8  = (L - row) & 7;               // slot (h8+row)&7 == L&7
      async16(A + (size_t)(row0 + row) * K + k0 + h8 * 8, As + cbase * 8);
      async16(W + (size_t)(col0 + row) * K + k0 + h8 * 8, Bs + cbase * 8);
    }
    __syncthreads();

#pragma unroll
    for (int ks = 0; ks < 2; ++ks) {
      const int c = ks * 4 + quad;
      bf16x8 af[4], bfr[4];
#pragma unroll
      for (int i = 0; i < 4; ++i) {
        const int m = wm + i * 16 + l16;
        af[i] = *(const bf16x8_a*)(As + m * 64 + ((c + m) & 7) * 8);
      }
#pragma unroll
      for (int j = 0; j < 4; ++j) {
        const int n = wn + j * 16 + l16;
        bfr[j] = *(const bf16x8_a*)(Bs + n * 64 + ((c + n) & 7) * 8);
      }
      if (!vblk) {
#pragma unroll
        for (int i = 0; i < 4; ++i)
#pragma unroll
          for (int j = 0; j < 4; ++j)
            acc[i][j] = __builtin_amdgcn_mfma_f32_16x16x32_bf16(af[i], bfr[j], acc[i][j], 0, 0, 0);
      } else {
        // swapped: D = W_frag * A_frag -> C^T (A/B fragment layouts are symmetric)
#pragma unroll
        for (int i = 0; i < 4; ++i)
#pragma unroll
          for (int j = 0; j < 4; ++j)
            acc[i][j] = __builtin_amdgcn_mfma_f32_16x16x32_bf16(bfr[j], af[i], acc[i][j], 0, 0, 0);
      }
    }
  }

  if (!vblk) {
    // C/D layout: col(n) = l16, row(m) = quad*4 + r (m89-verified)
#pragma unroll
    for (int j = 0; j < 4; ++j) {
      const int n = col0 + wn + j * 16 + l16;
      const float bn = bias[n];
      const int s  = n >> 10;
      const int h  = (n >> 6) & (NH - 1);
      const int hd = n & (NHD - 1);
      const float sc = (s == 0) ? SCALE_LOG2E : 1.0f;   // pre-scale Q
      u16* dst = C + (size_t)s * (NB * NH * NT * NHD);
#pragma unroll
      for (int i = 0; i < 4; ++i)
#pragma unroll
        for (int r = 0; r < 4; ++r) {
          const int m = row0 + wm + i * 16 + quad * 4 + r;
          const int b = m >> 11, t = m & (NT - 1);
          dst[(((size_t)b * NH + h) * NT + t) * NHD + hd] = f2b((acc[i][j][r] + bn) * sc);
        }
    }
  } else {
    // acc = C^T: n_out = col0+wn+j*16+quad*4+r (W dim), m_out = row0+wm+i*16+l16 (x dim)
    u16* dst = C + (size_t)2 * (NB * NH * NT * NHD);
#pragma unroll
    for (int j = 0; j < 4; ++j)
#pragma unroll
      for (int r = 0; r < 4; ++r) {
        const int n  = col0 + wn + j * 16 + quad * 4 + r;
        const float bn = bias[n];
        const int h  = (n >> 6) & (NH - 1);
        const int hd = n & (NHD - 1);
#pragma unroll
        for (int i = 0; i < 4; ++i) {
          const int m = row0 + wm + i * 16 + l16;
          const int b = m >> 11, t = m & (NT - 1);
          const int tl = t & 63;
          const int tp = (t & ~63) | (tl & 35) | ((tl & 12) << 1) | ((tl & 16) >> 2);
          dst[((size_t)(b * NH + h) * NHD + hd) * NT + tp] = f2b(acc[i][j][r] + bn);
        }
      }
  }
}

// ---------------- OUT GEMM: 128x64 tile (512 blocks = 2/CU), fp32 out -----------------
__global__ __launch_bounds__(256, 2)
void gemm_out(const u16* __restrict__ A, const u16* __restrict__ W,
              const float* __restrict__ bias, float* __restrict__ C) {
  constexpr int K = 1024;
  __shared__ alignas(16) u16 As[128 * 64];
  __shared__ alignas(16) u16 Bs[64 * 64];

  const int tid  = threadIdx.x;
  const int lane = tid & 63;
  const int wave = tid >> 6;
  const int l16  = lane & 15;
  const int quad = lane >> 4;
  const int row0 = blockIdx.x * 128;
  const int col0 = blockIdx.y * 64;
  const int wm   = wave * 32;

  const f32x4 z4 = {0.f, 0.f, 0.f, 0.f};
  f32x4 acc[2][4];
#pragma unroll
  for (int i = 0; i < 2; ++i)
#pragma unroll
    for (int j = 0; j < 4; ++j) acc[i][j] = z4;

  for (int k0 = 0; k0 < K; k0 += 64) {
    __syncthreads();
#pragma unroll
    for (int t = 0; t < 4; ++t) {                  // A: 1024 chunks
      const int cbase = wave * 64 + t * 256;
      const int L   = cbase + lane;
      const int row = L >> 3;
      const int h8  = (L - row) & 7;
      async16(A + (size_t)(row0 + row) * K + k0 + h8 * 8, As + cbase * 8);
    }
#pragma unroll
    for (int t = 0; t < 2; ++t) {                  // B: 512 chunks
      const int cbase = wave * 64 + t * 256;
      const int L   = cbase + lane;
      const int row = L >> 3;
      const int h8  = (L - row) & 7;
      async16(W + (size_t)(col0 + row) * K + k0 + h8 * 8, Bs + cbase * 8);
    }
    __syncthreads();

#pragma unroll
    for (int ks = 0; ks < 2; ++ks) {
      const int c = ks * 4 + quad;
      bf16x8 af[2], bfr[4];
#pragma unroll
      for (int i = 0; i < 2; ++i) {
        const int m = wm + i * 16 + l16;
        af[i] = *(const bf16x8_a*)(As + m * 64 + ((c + m) & 7) * 8);
      }
#pragma unroll
      for (int j = 0; j < 4; ++j) {
        const int n = j * 16 + l16;
        bfr[j] = *(const bf16x8_a*)(Bs + n * 64 + ((c + n) & 7) * 8);
      }
#pragma unroll
      for (int i = 0; i < 2; ++i)
#pragma unroll
        for (int j = 0; j < 4; ++j)
          acc[i][j] = __builtin_amdgcn_mfma_f32_16x16x32_bf16(af[i], bfr[j], acc[i][j], 0, 0, 0);
    }
  }

#pragma unroll
  for (int j = 0; j < 4; ++j) {
    const int n = col0 + j * 16 + l16;
    const float bn = bias[n];
#pragma unroll
    for (int i = 0; i < 2; ++i)
#pragma unroll
      for (int r = 0; r < 4; ++r) {
        const int m = row0 + wm + i * 16 + quad * 4 + r;
        C[(size_t)m * ND + n] = acc[i][j][r] + bn;
      }
  }
}

// ---------------- Flash attention v6: v4 geometry + counted-vmcnt 4-deep pipeline -----
// 256-thr blocks: 4 waves x 32 q-rows = 128 q/block; grid (32,16) = 512 blocks = 2/CU
// (LDS 64 KiB: K,V quad-buffered). Prefetch depth 3; per iter each wave waits
// s_waitcnt vmcnt(8) (its own 4 oldest loads = buffer t landed) then raw s_barrier ->
// no vmcnt(0) drain ever (T3/T4 minimal form). Tail stays uniform by re-staging tile 31
// into dead buffers. Per wave-iter: 16 ds_read_b128 for 32 MFMA; P never leaves VGPRs.
__global__ __launch_bounds__(256, 2)
void attn(const u16* __restrict__ Qb, const u16* __restrict__ Kb,
          const u16* __restrict__ Vb, u16* __restrict__ Yb) {
  __shared__ alignas(16) u16 Ks[4][64 * 64];
  __shared__ alignas(16) u16 Vt[4][64 * 64];

  const int tid  = threadIdx.x;
  const int lane = tid & 63;
  const int wave = tid >> 6;                    // 0..3
  const int l16  = lane & 15;
  const int quad = lane >> 4;

  const int bh = blockIdx.x;                    // b*NH + h
  const int q0 = blockIdx.y * 128;
  const u16* Q  = Qb + (size_t)bh * NT * NHD;
  const u16* Kg = Kb + (size_t)bh * NT * NHD;   // [key][hd]
  const u16* Vg = Vb + (size_t)bh * NHD * NT;   // [hd][tP], key-permuted per 64-block
  const int b = bh >> 4, h = bh & (NH - 1);
  u16* Y = Yb + (size_t)b * NT * ND + h * NHD;

  const int qw = q0 + wave * 32;                // 32 q-rows per wave

  // Q B-fragments (pre-scaled by SCALE_LOG2E in gemm_qkv), resident
  bf16x8 qf[2][2];                              // [q-half][ks]
#pragma unroll
  for (int n = 0; n < 2; ++n)
#pragma unroll
    for (int ks = 0; ks < 2; ++ks)
      qf[n][ks] = *(const bf16x8_a*)(Q + (size_t)(qw + n * 16 + l16) * NHD + ks * 32 + quad * 8);

  const f32x4 z4 = {0.f, 0.f, 0.f, 0.f};
  f32x4 o[2][4];
  float lacc[2] = {0.f, 0.f};
#pragma unroll
  for (int m = 0; m < 2; ++m)
#pragma unroll
    for (int n = 0; n < 4; ++n) o[m][n] = z4;

  auto stage = [&](int key0, int buf) {
#pragma unroll
    for (int cc = 0; cc < 2; ++cc) {            // 512 chunks per matrix / 256 threads
      const int cbase = cc * 256 + wave * 64;
      const int L   = cbase + lane;
      const int row = L >> 3;
      const int h8  = (L - row) & 7;            // slot (h8+row)&7 == L&7
      async16(Kg + (size_t)(key0 + row) * NHD + h8 * 8, &Ks[buf][0] + cbase * 8);
      async16(Vg + (size_t)row * NT + key0 + h8 * 8, &Vt[buf][0] + cbase * 8);
    }
  };

  // prologue: prefetch depth 3, no drain (counted waits in the loop handle it)
  stage(0, 0);
  stage(64, 1);
  stage(128, 2);

  for (int kb = 0; kb < NT / 64; ++kb) {
    // own 4 oldest outstanding loads = buffer kb; all waves verify theirs, then sync
    asm volatile("s_waitcnt vmcnt(8)" ::: "memory");
    __builtin_amdgcn_s_barrier();
    __builtin_amdgcn_sched_barrier(0);

    // stage into the buffer freed at the barrier (tail: re-stage tile 31, dead buffers)
    const int st = (kb + 3 < NT / 64) ? kb + 3 : NT / 64 - 1;
    stage(st * 64, (kb + 3) & 3);

    const int buf = kb & 3;

    // S^T = K Q^T : s[km][qn] -> key = km*16+quad*4+r, q = qn*16+l16
    f32x4 s[4][2];
#pragma unroll
    for (int km = 0; km < 4; ++km)
#pragma unroll
      for (int qn = 0; qn < 2; ++qn) s[km][qn] = z4;
#pragma unroll
    for (int ks = 0; ks < 2; ++ks) {
      const int c = ks * 4 + quad;
      bf16x8 kf[4];
#pragma unroll
      for (int km = 0; km < 4; ++km) {
        const int key = km * 16 + l16;
        kf[km] = *(const bf16x8_a*)(&Ks[buf][0] + key * 64 + ((c + key) & 7) * 8);
      }
#pragma unroll
      for (int km = 0; km < 4; ++km)
#pragma unroll
        for (int qn = 0; qn < 2; ++qn)
          s[km][qn] = __builtin_amdgcn_mfma_f32_16x16x32_bf16(kf[km], qf[qn][ks], s[km][qn], 0, 0, 0);
    }

    // softmax (scores pre-scaled): p = 2^s; per-lane partial row sums
#pragma unroll
    for (int qn = 0; qn < 2; ++qn) {
      float rs = 0.f;
#pragma unroll
      for (int km = 0; km < 4; ++km)
#pragma unroll
        for (int r = 0; r < 4; ++r) {
          const float p = __builtin_amdgcn_exp2f(s[km][qn][r]);
          s[km][qn][r] = p;
          rs += p;
        }
      lacc[qn] += rs;
    }

    // O += P V ; pf[qm][ks] element e = P[q][32ks+16(e>>2)+4quad+(e&3)] (in registers)
#pragma unroll
    for (int ks = 0; ks < 2; ++ks) {
      const int c = ks * 4 + quad;
      bf16x8 vf[4];
#pragma unroll
      for (int hn = 0; hn < 4; ++hn) {
        const int hd = hn * 16 + l16;
        vf[hn] = *(const bf16x8_a*)(&Vt[buf][0] + hd * 64 + ((c + hd) & 7) * 8);
      }
#pragma unroll
      for (int qm = 0; qm < 2; ++qm) {
        u32x4 pwv;
        pwv[0] = pack2_tr(s[2 * ks][qm][0],     s[2 * ks][qm][1]);
        pwv[1] = pack2_tr(s[2 * ks][qm][2],     s[2 * ks][qm][3]);
        pwv[2] = pack2_tr(s[2 * ks + 1][qm][0], s[2 * ks + 1][qm][1]);
        pwv[3] = pack2_tr(s[2 * ks + 1][qm][2], s[2 * ks + 1][qm][3]);
        const bf16x8 pf = __builtin_bit_cast(bf16x8, pwv);
#pragma unroll
        for (int hn = 0; hn < 4; ++hn)
          o[qm][hn] = __builtin_amdgcn_mfma_f32_16x16x32_bf16(pf, vf[hn], o[qm][hn], 0, 0, 0);
      }
    }
  }

  // epilogue: reduce l across quads (q lives at l16), redistribute, O/l -> Y
#pragma unroll
  for (int qm = 0; qm < 2; ++qm) {
    float l = lacc[qm];
    l += __shfl_xor(l, 16);
    l += __shfl_xor(l, 32);
#pragma unroll
    for (int r = 0; r < 4; ++r) {
      const float inv = 1.0f / __shfl(l, quad * 4 + r);
      const int t = qw + qm * 16 + quad * 4 + r;
#pragma unroll
      for (int hn = 0; hn < 4; ++hn)
        Y[(size_t)t * ND + hn * 16 + l16] = f2b(o[qm][hn][r] * inv);
    }
  }
}

extern "C" void kernel_launch(void* const* d_in, const int* in_sizes, int n_in,
                              void* d_out, int out_size, void* d_ws, size_t ws_size,
                              hipStream_t stream) {
  // inputs fp32, output fp32 (round-6-verified).
  const float* x     = (const float*)d_in[0];
  const float* w_qkv = (const float*)d_in[2];
  const float* b_qkv = (const float*)d_in[3];
  const float* w_out = (const float*)d_in[4];
  const float* b_out = (const float*)d_in[5];

  u16* ws = (u16*)d_ws;
  const size_t perbuf = (size_t)NB * NH * NT * NHD;  // 4,194,304 elems
  u16* qkv   = ws;                                   // [0,24MB): Q|K|V^T (bf16)
  u16* xb    = ws + 3 * perbuf;                      // [24,32MB): x bf16, reused as y
  u16* y     = xb;
  u16* wqkvb = ws + 4 * perbuf;                      // [32,38MB): w_qkv bf16
  u16* woutb = wqkvb + (size_t)3 * ND * ND;          // [38,40MB): w_out bf16

  cvt_all<<<dim3(4096), dim3(256), 0, stream>>>(x, w_qkv, w_out, xb, wqkvb, woutb);
  gemm_qkv<<<dim3(32, 24), dim3(256), 0, stream>>>(xb, wqkvb, b_qkv, qkv);
  attn<<<dim3(32, 16), dim3(256), 0, stream>>>(qkv, qkv + perbuf, qkv + 2 * perbuf, y);
  gemm_out<<<dim3(32, 16), dim3(256), 0, stream>>>(y, woutb, b_out, (float*)d_out);
}

// Round 6
// 187.760 us; speedup vs baseline: 1.0444x; 1.0444x over previous
//
#include <hip/hip_runtime.h>
#include <stdint.h>

typedef unsigned short u16;
typedef __attribute__((ext_vector_type(8))) short bf16x8;   // 8 bf16 = 4 VGPRs
typedef bf16x8 __attribute__((may_alias)) bf16x8_a;
typedef __attribute__((ext_vector_type(4))) float f32x4;
typedef f32x4 __attribute__((may_alias)) f32x4_a;
typedef __attribute__((ext_vector_type(4))) uint32_t u32x4;

#define GLOBAL_AS __attribute__((address_space(1)))
#define LDS_AS    __attribute__((address_space(3)))

#define NB 2
#define NT 2048
#define ND 1024
#define NH 16
#define NHD 64
#define SCALE_LOG2E 0.1803368801111f   // (1/sqrt(64)) * log2(e)

static __device__ __forceinline__ u16 f2b(float f) {  // fp32 -> bf16 RNE
  uint32_t x = __builtin_bit_cast(uint32_t, f);
  x += 0x7fffu + ((x >> 16) & 1u);
  return (u16)(x >> 16);
}
// pack two fp32 -> two bf16 (truncation), one v_perm_b32
static __device__ __forceinline__ uint32_t pack2_tr(float lo, float hi) {
  return __builtin_amdgcn_perm(__builtin_bit_cast(uint32_t, hi),
                               __builtin_bit_cast(uint32_t, lo), 0x07060302u);
}

// 16B global->LDS DMA; LDS dest = wave-uniform base + lane*16 (m97/m104)
static __device__ __forceinline__ void async16(const u16* g, u16* l) {
  __builtin_amdgcn_global_load_lds((const GLOBAL_AS uint32_t*)g, (LDS_AS uint32_t*)l, 16, 0, 0);
}

// ---------------- fused fp32 -> bf16 convert for x, w_qkv, w_out (one launch) ---------
#define XN8   524288   // 4,194,304 / 8
#define WQN8  393216   // 3,145,728 / 8
__global__ __launch_bounds__(256)
void cvt_all(const float* __restrict__ x, const float* __restrict__ wq,
             const float* __restrict__ wo, u16* __restrict__ xb,
             u16* __restrict__ wqb, u16* __restrict__ wob) {
  int i = blockIdx.x * blockDim.x + threadIdx.x;
  const float* src;
  u16* dst;
  if (i < XN8)              { src = x;  dst = xb; }
  else if (i < XN8 + WQN8)  { src = wq; dst = wqb; i -= XN8; }
  else                      { src = wo; dst = wob; i -= XN8 + WQN8; }
  const f32x4 a = ((const f32x4_a*)src)[2 * i];
  const f32x4 b = ((const f32x4_a*)src)[2 * i + 1];
  bf16x8 o;
#pragma unroll
  for (int e = 0; e < 4; ++e) {
    ((short*)&o)[e]     = (short)f2b(a[e]);
    ((short*)&o)[e + 4] = (short)f2b(b[e]);
  }
  ((bf16x8_a*)dst)[i] = o;
}

// ---------------- QKV GEMM (m97 + swizzle): C = A(M,K)*W(N,K)^T + bias, K=1024 --------
// 128x128 tile, BK=64, global_load_lds staging, rotation swizzle (slot=(chunk+row)&7).
// Q block (n<1024): values pre-scaled by SCALE_LOG2E (attn then does exp2(s) directly).
// Q,K blocks: scatter [s][(b*NH+h)*NT+t][hd].
// V blocks (col0>=2048): swapped MFMA -> C^T; V^T store [bh*NHD+hd][tP] where tP is a
//   key-permutation within each 64-block: p = (k&32)|((k&12)<<1)|((k&16)>>2)|(k&3),
//   chosen so attn's PV B-fragment (keys 32ks+16(e>>2)+4quad+(e&3)) is one b128 read.
__global__ __launch_bounds__(256, 2)
void gemm_qkv(const u16* __restrict__ A, const u16* __restrict__ W,
              const float* __restrict__ bias, u16* __restrict__ C) {
  constexpr int K = 1024;
  __shared__ alignas(16) u16 As[128 * 64];
  __shared__ alignas(16) u16 Bs[128 * 64];

  const int tid  = threadIdx.x;
  const int lane = tid & 63;
  const int wave = tid >> 6;
  const int l16  = lane & 15;
  const int quad = lane >> 4;
  const int row0 = blockIdx.x * 128;
  const int col0 = blockIdx.y * 128;
  const int wm   = (wave >> 1) * 64;
  const int wn   = (wave & 1) * 64;
  const bool vblk = (col0 >= 2048);            // block-uniform

  const f32x4 z4 = {0.f, 0.f, 0.f, 0.f};
  f32x4 acc[4][4];
#pragma unroll
  for (int i = 0; i < 4; ++i)
#pragma unroll
    for (int j = 0; j < 4; ++j) acc[i][j] = z4;

  for (int k0 = 0; k0 < K; k0 += 64) {
    __syncthreads();
#pragma unroll
    for (int t = 0; t < 4; ++t) {
      const int cbase = wave * 64 + t * 256;
      const int L   = cbase + lane;
      const int row = L >> 3;
      const int h8  = (L - row) & 7;               // slot (h8+row)&7 == L&7
      async16(A + (size_t)(row0 + row) * K + k0 + h8 * 8, As + cbase * 8);
      async16(W + (size_t)(col0 + row) * K + k0 + h8 * 8, Bs + cbase * 8);
    }
    __syncthreads();

#pragma unroll
    for (int ks = 0; ks < 2; ++ks) {
      const int c = ks * 4 + quad;
      bf16x8 af[4], bfr[4];
#pragma unroll
      for (int i = 0; i < 4; ++i) {
        const int m = wm + i * 16 + l16;
        af[i] = *(const bf16x8_a*)(As + m * 64 + ((c + m) & 7) * 8);
      }
#pragma unroll
      for (int j = 0; j < 4; ++j) {
        const int n = wn + j * 16 + l16;
        bfr[j] = *(const bf16x8_a*)(Bs + n * 64 + ((c + n) & 7) * 8);
      }
      if (!vblk) {
#pragma unroll
        for (int i = 0; i < 4; ++i)
#pragma unroll
          for (int j = 0; j < 4; ++j)
            acc[i][j] = __builtin_amdgcn_mfma_f32_16x16x32_bf16(af[i], bfr[j], acc[i][j], 0, 0, 0);
      } else {
        // swapped: D = W_frag * A_frag -> C^T (A/B fragment layouts are symmetric)
#pragma unroll
        for (int i = 0; i < 4; ++i)
#pragma unroll
          for (int j = 0; j < 4; ++j)
            acc[i][j] = __builtin_amdgcn_mfma_f32_16x16x32_bf16(bfr[j], af[i], acc[i][j], 0, 0, 0);
      }
    }
  }

  if (!vblk) {
    // C/D layout: col(n) = l16, row(m) = quad*4 + r (m89-verified)
#pragma unroll
    for (int j = 0; j < 4; ++j) {
      const int n = col0 + wn + j * 16 + l16;
      const float bn = bias[n];
      const int s  = n >> 10;
      const int h  = (n >> 6) & (NH - 1);
      const int hd = n & (NHD - 1);
      const float sc = (s == 0) ? SCALE_LOG2E : 1.0f;   // pre-scale Q
      u16* dst = C + (size_t)s * (NB * NH * NT * NHD);
#pragma unroll
      for (int i = 0; i < 4; ++i)
#pragma unroll
        for (int r = 0; r < 4; ++r) {
          const int m = row0 + wm + i * 16 + quad * 4 + r;
          const int b = m >> 11, t = m & (NT - 1);
          dst[(((size_t)b * NH + h) * NT + t) * NHD + hd] = f2b((acc[i][j][r] + bn) * sc);
        }
    }
  } else {
    // acc = C^T: n_out = col0+wn+j*16+quad*4+r (W dim), m_out = row0+wm+i*16+l16 (x dim)
    u16* dst = C + (size_t)2 * (NB * NH * NT * NHD);
#pragma unroll
    for (int j = 0; j < 4; ++j)
#pragma unroll
      for (int r = 0; r < 4; ++r) {
        const int n  = col0 + wn + j * 16 + quad * 4 + r;
        const float bn = bias[n];
        const int h  = (n >> 6) & (NH - 1);
        const int hd = n & (NHD - 1);
#pragma unroll
        for (int i = 0; i < 4; ++i) {
          const int m = row0 + wm + i * 16 + l16;
          const int b = m >> 11, t = m & (NT - 1);
          const int tl = t & 63;
          const int tp = (t & ~63) | (tl & 35) | ((tl & 12) << 1) | ((tl & 16) >> 2);
          dst[((size_t)(b * NH + h) * NHD + hd) * NT + tp] = f2b(acc[i][j][r] + bn);
        }
      }
  }
}

// ---------------- OUT GEMM: 128x64 tile (512 blocks = 2/CU), fp32 out -----------------
__global__ __launch_bounds__(256, 2)
void gemm_out(const u16* __restrict__ A, const u16* __restrict__ W,
              const float* __restrict__ bias, float* __restrict__ C) {
  constexpr int K = 1024;
  __shared__ alignas(16) u16 As[128 * 64];
  __shared__ alignas(16) u16 Bs[64 * 64];

  const int tid  = threadIdx.x;
  const int lane = tid & 63;
  const int wave = tid >> 6;
  const int l16  = lane & 15;
  const int quad = lane >> 4;
  const int row0 = blockIdx.x * 128;
  const int col0 = blockIdx.y * 64;
  const int wm   = wave * 32;

  const f32x4 z4 = {0.f, 0.f, 0.f, 0.f};
  f32x4 acc[2][4];
#pragma unroll
  for (int i = 0; i < 2; ++i)
#pragma unroll
    for (int j = 0; j < 4; ++j) acc[i][j] = z4;

  for (int k0 = 0; k0 < K; k0 += 64) {
    __syncthreads();
#pragma unroll
    for (int t = 0; t < 4; ++t) {                  // A: 1024 chunks
      const int cbase = wave * 64 + t * 256;
      const int L   = cbase + lane;
      const int row = L >> 3;
      const int h8  = (L - row) & 7;
      async16(A + (size_t)(row0 + row) * K + k0 + h8 * 8, As + cbase * 8);
    }
#pragma unroll
    for (int t = 0; t < 2; ++t) {                  // B: 512 chunks
      const int cbase = wave * 64 + t * 256;
      const int L   = cbase + lane;
      const int row = L >> 3;
      const int h8  = (L - row) & 7;
      async16(W + (size_t)(col0 + row) * K + k0 + h8 * 8, Bs + cbase * 8);
    }
    __syncthreads();

#pragma unroll
    for (int ks = 0; ks < 2; ++ks) {
      const int c = ks * 4 + quad;
      bf16x8 af[2], bfr[4];
#pragma unroll
      for (int i = 0; i < 2; ++i) {
        const int m = wm + i * 16 + l16;
        af[i] = *(const bf16x8_a*)(As + m * 64 + ((c + m) & 7) * 8);
      }
#pragma unroll
      for (int j = 0; j < 4; ++j) {
        const int n = j * 16 + l16;
        bfr[j] = *(const bf16x8_a*)(Bs + n * 64 + ((c + n) & 7) * 8);
      }
#pragma unroll
      for (int i = 0; i < 2; ++i)
#pragma unroll
        for (int j = 0; j < 4; ++j)
          acc[i][j] = __builtin_amdgcn_mfma_f32_16x16x32_bf16(af[i], bfr[j], acc[i][j], 0, 0, 0);
    }
  }

#pragma unroll
  for (int j = 0; j < 4; ++j) {
    const int n = col0 + j * 16 + l16;
    const float bn = bias[n];
#pragma unroll
    for (int i = 0; i < 2; ++i)
#pragma unroll
      for (int r = 0; r < 4; ++r) {
        const int m = row0 + wm + i * 16 + quad * 4 + r;
        C[(size_t)m * ND + n] = acc[i][j][r] + bn;
      }
  }
}

// ---------------- Flash attention v7: v4 wave-code, 512-thr blocks, 1 block/CU --------
// 512-thr blocks: 8 waves x 32 q-rows = 256 q/block; grid (32,8) = 256 blocks = 1/CU
// (LDS 32 KiB: K,V double-buffered, shared by 8 waves). Staging per CU per iter halves
// vs v4 (16 KB, 1 async16-pair/thread); one barrier syncs the CU. 2 waves/SIMD kept
// (v5 showed 1/SIMD is fatal; v6 showed counted-vmcnt on 2-phase regresses -> revert
// to plain __syncthreads dbuf discipline). blockIdx: id%8 = bh%8 -> all q-blocks of a
// head on one XCD, K/V L2-resident (4 heads x 512 KB = 2 MB/XCD).
__global__ __launch_bounds__(512, 1)
void attn(const u16* __restrict__ Qb, const u16* __restrict__ Kb,
          const u16* __restrict__ Vb, u16* __restrict__ Yb) {
  __shared__ alignas(16) u16 Ks[2][64 * 64];
  __shared__ alignas(16) u16 Vt[2][64 * 64];

  const int tid  = threadIdx.x;
  const int lane = tid & 63;
  const int wave = tid >> 6;                    // 0..7
  const int l16  = lane & 15;
  const int quad = lane >> 4;

  const int bh = blockIdx.x;                    // b*NH + h
  const int q0 = blockIdx.y * 256;
  const u16* Q  = Qb + (size_t)bh * NT * NHD;
  const u16* Kg = Kb + (size_t)bh * NT * NHD;   // [key][hd]
  const u16* Vg = Vb + (size_t)bh * NHD * NT;   // [hd][tP], key-permuted per 64-block
  const int b = bh >> 4, h = bh & (NH - 1);
  u16* Y = Yb + (size_t)b * NT * ND + h * NHD;

  const int qw = q0 + wave * 32;                // 32 q-rows per wave

  // Q B-fragments (pre-scaled by SCALE_LOG2E in gemm_qkv), resident
  bf16x8 qf[2][2];                              // [q-half][ks]
#pragma unroll
  for (int n = 0; n < 2; ++n)
#pragma unroll
    for (int ks = 0; ks < 2; ++ks)
      qf[n][ks] = *(const bf16x8_a*)(Q + (size_t)(qw + n * 16 + l16) * NHD + ks * 32 + quad * 8);

  const f32x4 z4 = {0.f, 0.f, 0.f, 0.f};
  f32x4 o[2][4];
  float lacc[2] = {0.f, 0.f};
#pragma unroll
  for (int m = 0; m < 2; ++m)
#pragma unroll
    for (int n = 0; n < 4; ++n) o[m][n] = z4;

  auto stage = [&](int key0, int buf) {
    // 512 chunks per matrix / 512 threads: 1 K-chunk + 1 V-chunk per thread
    const int cbase = wave * 64;                // wave-uniform
    const int L   = cbase + lane;
    const int row = L >> 3;
    const int h8  = (L - row) & 7;              // slot (h8+row)&7 == L&7
    async16(Kg + (size_t)(key0 + row) * NHD + h8 * 8, &Ks[buf][0] + cbase * 8);
    async16(Vg + (size_t)row * NT + key0 + h8 * 8, &Vt[buf][0] + cbase * 8);
  };

  stage(0, 0);
  __syncthreads();                              // drain prologue DMA

  for (int kb = 0; kb < NT / 64; ++kb) {
    const int buf = kb & 1;
    if (kb + 1 < NT / 64) stage((kb + 1) * 64, buf ^ 1);   // prefetch, in flight all iter

    // S^T = K Q^T : s[km][qn] -> key = km*16+quad*4+r, q = qn*16+l16
    f32x4 s[4][2];
#pragma unroll
    for (int km = 0; km < 4; ++km)
#pragma unroll
      for (int qn = 0; qn < 2; ++qn) s[km][qn] = z4;
#pragma unroll
    for (int ks = 0; ks < 2; ++ks) {
      const int c = ks * 4 + quad;
      bf16x8 kf[4];
#pragma unroll
      for (int km = 0; km < 4; ++km) {
        const int key = km * 16 + l16;
        kf[km] = *(const bf16x8_a*)(&Ks[buf][0] + key * 64 + ((c + key) & 7) * 8);
      }
#pragma unroll
      for (int km = 0; km < 4; ++km)
#pragma unroll
        for (int qn = 0; qn < 2; ++qn)
          s[km][qn] = __builtin_amdgcn_mfma_f32_16x16x32_bf16(kf[km], qf[qn][ks], s[km][qn], 0, 0, 0);
    }

    // softmax (scores pre-scaled): p = 2^s; per-lane partial row sums
#pragma unroll
    for (int qn = 0; qn < 2; ++qn) {
      float rs = 0.f;
#pragma unroll
      for (int km = 0; km < 4; ++km)
#pragma unroll
        for (int r = 0; r < 4; ++r) {
          const float p = __builtin_amdgcn_exp2f(s[km][qn][r]);
          s[km][qn][r] = p;
          rs += p;
        }
      lacc[qn] += rs;
    }

    // O += P V ; pf[qm][ks] element e = P[q][32ks+16(e>>2)+4quad+(e&3)] (in registers)
#pragma unroll
    for (int ks = 0; ks < 2; ++ks) {
      const int c = ks * 4 + quad;
      bf16x8 vf[4];
#pragma unroll
      for (int hn = 0; hn < 4; ++hn) {
        const int hd = hn * 16 + l16;
        vf[hn] = *(const bf16x8_a*)(&Vt[buf][0] + hd * 64 + ((c + hd) & 7) * 8);
      }
#pragma unroll
      for (int qm = 0; qm < 2; ++qm) {
        u32x4 pwv;
        pwv[0] = pack2_tr(s[2 * ks][qm][0],     s[2 * ks][qm][1]);
        pwv[1] = pack2_tr(s[2 * ks][qm][2],     s[2 * ks][qm][3]);
        pwv[2] = pack2_tr(s[2 * ks + 1][qm][0], s[2 * ks + 1][qm][1]);
        pwv[3] = pack2_tr(s[2 * ks + 1][qm][2], s[2 * ks + 1][qm][3]);
        const bf16x8 pf = __builtin_bit_cast(bf16x8, pwv);
#pragma unroll
        for (int hn = 0; hn < 4; ++hn)
          o[qm][hn] = __builtin_amdgcn_mfma_f32_16x16x32_bf16(pf, vf[hn], o[qm][hn], 0, 0, 0);
      }
    }

    __syncthreads();   // drains prefetch DMA (overlapped with compute) + buf protection
  }

  // epilogue: reduce l across quads (q lives at l16), redistribute, O/l -> Y
#pragma unroll
  for (int qm = 0; qm < 2; ++qm) {
    float l = lacc[qm];
    l += __shfl_xor(l, 16);
    l += __shfl_xor(l, 32);
#pragma unroll
    for (int r = 0; r < 4; ++r) {
      const float inv = 1.0f / __shfl(l, quad * 4 + r);
      const int t = qw + qm * 16 + quad * 4 + r;
#pragma unroll
      for (int hn = 0; hn < 4; ++hn)
        Y[(size_t)t * ND + hn * 16 + l16] = f2b(o[qm][hn][r] * inv);
    }
  }
}

extern "C" void kernel_launch(void* const* d_in, const int* in_sizes, int n_in,
                              void* d_out, int out_size, void* d_ws, size_t ws_size,
                              hipStream_t stream) {
  // inputs fp32, output fp32 (round-6-verified).
  const float* x     = (const float*)d_in[0];
  const float* w_qkv = (const float*)d_in[2];
  const float* b_qkv = (const float*)d_in[3];
  const float* w_out = (const float*)d_in[4];
  const float* b_out = (const float*)d_in[5];

  u16* ws = (u16*)d_ws;
  const size_t perbuf = (size_t)NB * NH * NT * NHD;  // 4,194,304 elems
  u16* qkv   = ws;                                   // [0,24MB): Q|K|V^T (bf16)
  u16* xb    = ws + 3 * perbuf;                      // [24,32MB): x bf16, reused as y
  u16* y     = xb;
  u16* wqkvb = ws + 4 * perbuf;                      // [32,38MB): w_qkv bf16
  u16* woutb = wqkvb + (size_t)3 * ND * ND;          // [38,40MB): w_out bf16

  cvt_all<<<dim3(4096), dim3(256), 0, stream>>>(x, w_qkv, w_out, xb, wqkvb, woutb);
  gemm_qkv<<<dim3(32, 24), dim3(256), 0, stream>>>(xb, wqkvb, b_qkv, qkv);
  attn<<<dim3(32, 8), dim3(512), 0, stream>>>(qkv, qkv + perbuf, qkv + 2 * perbuf, y);
  gemm_out<<<dim3(32, 16), dim3(256), 0, stream>>>(y, woutb, b_out, (float*)d_out);
}

// Round 8
// 184.895 us; speedup vs baseline: 1.0605x; 1.0155x over previous
//
#include <hip/hip_runtime.h>
#include <stdint.h>

typedef unsigned short u16;
typedef __attribute__((ext_vector_type(8))) short bf16x8;   // 8 bf16 = 4 VGPRs
typedef bf16x8 __attribute__((may_alias)) bf16x8_a;
typedef __attribute__((ext_vector_type(4))) float f32x4;
typedef f32x4 __attribute__((may_alias)) f32x4_a;
typedef __attribute__((ext_vector_type(4))) uint32_t u32x4;

#define GLOBAL_AS __attribute__((address_space(1)))
#define LDS_AS    __attribute__((address_space(3)))

#define NB 2
#define NT 2048
#define ND 1024
#define NH 16
#define NHD 64
#define SCALE_LOG2E 0.1803368801111f   // (1/sqrt(64)) * log2(e)

static __device__ __forceinline__ u16 f2b(float f) {  // fp32 -> bf16 RNE
  uint32_t x = __builtin_bit_cast(uint32_t, f);
  x += 0x7fffu + ((x >> 16) & 1u);
  return (u16)(x >> 16);
}
// pack two fp32 -> two bf16 (truncation), one v_perm_b32
static __device__ __forceinline__ uint32_t pack2_tr(float lo, float hi) {
  return __builtin_amdgcn_perm(__builtin_bit_cast(uint32_t, hi),
                               __builtin_bit_cast(uint32_t, lo), 0x07060302u);
}

// 16B global->LDS DMA; LDS dest = wave-uniform base + lane*16 (m97/m104)
static __device__ __forceinline__ void async16(const u16* g, u16* l) {
  __builtin_amdgcn_global_load_lds((const GLOBAL_AS uint32_t*)g, (LDS_AS uint32_t*)l, 16, 0, 0);
}

// ---------------- fused fp32 -> bf16 convert for x, w_qkv, w_out (one launch) ---------
#define XN8   524288   // 4,194,304 / 8
#define WQN8  393216   // 3,145,728 / 8
__global__ __launch_bounds__(256)
void cvt_all(const float* __restrict__ x, const float* __restrict__ wq,
             const float* __restrict__ wo, u16* __restrict__ xb,
             u16* __restrict__ wqb, u16* __restrict__ wob) {
  int i = blockIdx.x * blockDim.x + threadIdx.x;
  const float* src;
  u16* dst;
  if (i < XN8)              { src = x;  dst = xb; }
  else if (i < XN8 + WQN8)  { src = wq; dst = wqb; i -= XN8; }
  else                      { src = wo; dst = wob; i -= XN8 + WQN8; }
  const f32x4 a = ((const f32x4_a*)src)[2 * i];
  const f32x4 b = ((const f32x4_a*)src)[2 * i + 1];
  bf16x8 o;
#pragma unroll
  for (int e = 0; e < 4; ++e) {
    ((short*)&o)[e]     = (short)f2b(a[e]);
    ((short*)&o)[e + 4] = (short)f2b(b[e]);
  }
  ((bf16x8_a*)dst)[i] = o;
}

// ---------------- QKV GEMM (m97 + swizzle): C = A(M,K)*W(N,K)^T + bias, K=1024 --------
// 128x128 tile, BK=64, global_load_lds staging, rotation swizzle (slot=(chunk+row)&7).
// Q block (n<1024): values pre-scaled by SCALE_LOG2E (attn then does exp2(s) directly).
// Q,K blocks: scatter [s][(b*NH+h)*NT+t][hd].
// V blocks (col0>=2048): swapped MFMA -> C^T; V^T store [bh*NHD+hd][tP] where tP is a
//   key-permutation within each 64-block: p = (k&32)|((k&12)<<1)|((k&16)>>2)|(k&3),
//   chosen so attn's PV B-fragment (keys 32ks+16(e>>2)+4quad+(e&3)) is one b128 read.
__global__ __launch_bounds__(256, 2)
void gemm_qkv(const u16* __restrict__ A, const u16* __restrict__ W,
              const float* __restrict__ bias, u16* __restrict__ C) {
  constexpr int K = 1024;
  __shared__ alignas(16) u16 As[128 * 64];
  __shared__ alignas(16) u16 Bs[128 * 64];

  const int tid  = threadIdx.x;
  const int lane = tid & 63;
  const int wave = tid >> 6;
  const int l16  = lane & 15;
  const int quad = lane >> 4;
  const int row0 = blockIdx.x * 128;
  const int col0 = blockIdx.y * 128;
  const int wm   = (wave >> 1) * 64;
  const int wn   = (wave & 1) * 64;
  const bool vblk = (col0 >= 2048);            // block-uniform

  const f32x4 z4 = {0.f, 0.f, 0.f, 0.f};
  f32x4 acc[4][4];
#pragma unroll
  for (int i = 0; i < 4; ++i)
#pragma unroll
    for (int j = 0; j < 4; ++j) acc[i][j] = z4;

  for (int k0 = 0; k0 < K; k0 += 64) {
    __syncthreads();
#pragma unroll
    for (int t = 0; t < 4; ++t) {
      const int cbase = wave * 64 + t * 256;
      const int L   = cbase + lane;
      const int row = L >> 3;
      const int h8  = (L - row) & 7;               // slot (h8+row)&7 == L&7
      async16(A + (size_t)(row0 + row) * K + k0 + h8 * 8, As + cbase * 8);
      async16(W + (size_t)(col0 + row) * K + k0 + h8 * 8, Bs + cbase * 8);
    }
    __syncthreads();

#pragma unroll
    for (int ks = 0; ks < 2; ++ks) {
      const int c = ks * 4 + quad;
      bf16x8 af[4], bfr[4];
#pragma unroll
      for (int i = 0; i < 4; ++i) {
        const int m = wm + i * 16 + l16;
        af[i] = *(const bf16x8_a*)(As + m * 64 + ((c + m) & 7) * 8);
      }
#pragma unroll
      for (int j = 0; j < 4; ++j) {
        const int n = wn + j * 16 + l16;
        bfr[j] = *(const bf16x8_a*)(Bs + n * 64 + ((c + n) & 7) * 8);
      }
      if (!vblk) {
#pragma unroll
        for (int i = 0; i < 4; ++i)
#pragma unroll
          for (int j = 0; j < 4; ++j)
            acc[i][j] = __builtin_amdgcn_mfma_f32_16x16x32_bf16(af[i], bfr[j], acc[i][j], 0, 0, 0);
      } else {
        // swapped: D = W_frag * A_frag -> C^T (A/B fragment layouts are symmetric)
#pragma unroll
        for (int i = 0; i < 4; ++i)
#pragma unroll
          for (int j = 0; j < 4; ++j)
            acc[i][j] = __builtin_amdgcn_mfma_f32_16x16x32_bf16(bfr[j], af[i], acc[i][j], 0, 0, 0);
      }
    }
  }

  if (!vblk) {
    // C/D layout: col(n) = l16, row(m) = quad*4 + r (m89-verified)
#pragma unroll
    for (int j = 0; j < 4; ++j) {
      const int n = col0 + wn + j * 16 + l16;
      const float bn = bias[n];
      const int s  = n >> 10;
      const int h  = (n >> 6) & (NH - 1);
      const int hd = n & (NHD - 1);
      const float sc = (s == 0) ? SCALE_LOG2E : 1.0f;   // pre-scale Q
      u16* dst = C + (size_t)s * (NB * NH * NT * NHD);
#pragma unroll
      for (int i = 0; i < 4; ++i)
#pragma unroll
        for (int r = 0; r < 4; ++r) {
          const int m = row0 + wm + i * 16 + quad * 4 + r;
          const int b = m >> 11, t = m & (NT - 1);
          dst[(((size_t)b * NH + h) * NT + t) * NHD + hd] = f2b((acc[i][j][r] + bn) * sc);
        }
    }
  } else {
    // acc = C^T: n_out = col0+wn+j*16+quad*4+r (W dim), m_out = row0+wm+i*16+l16 (x dim)
    u16* dst = C + (size_t)2 * (NB * NH * NT * NHD);
#pragma unroll
    for (int j = 0; j < 4; ++j)
#pragma unroll
      for (int r = 0; r < 4; ++r) {
        const int n  = col0 + wn + j * 16 + quad * 4 + r;
        const float bn = bias[n];
        const int h  = (n >> 6) & (NH - 1);
        const int hd = n & (NHD - 1);
#pragma unroll
        for (int i = 0; i < 4; ++i) {
          const int m = row0 + wm + i * 16 + l16;
          const int b = m >> 11, t = m & (NT - 1);
          const int tl = t & 63;
          const int tp = (t & ~63) | (tl & 35) | ((tl & 12) << 1) | ((tl & 16) >> 2);
          dst[((size_t)(b * NH + h) * NHD + hd) * NT + tp] = f2b(acc[i][j][r] + bn);
        }
      }
  }
}

// ---------------- OUT GEMM: 128x64 tile (512 blocks = 2/CU), fp32 out -----------------
__global__ __launch_bounds__(256, 2)
void gemm_out(const u16* __restrict__ A, const u16* __restrict__ W,
              const float* __restrict__ bias, float* __restrict__ C) {
  constexpr int K = 1024;
  __shared__ alignas(16) u16 As[128 * 64];
  __shared__ alignas(16) u16 Bs[64 * 64];

  const int tid  = threadIdx.x;
  const int lane = tid & 63;
  const int wave = tid >> 6;
  const int l16  = lane & 15;
  const int quad = lane >> 4;
  const int row0 = blockIdx.x * 128;
  const int col0 = blockIdx.y * 64;
  const int wm   = wave * 32;

  const f32x4 z4 = {0.f, 0.f, 0.f, 0.f};
  f32x4 acc[2][4];
#pragma unroll
  for (int i = 0; i < 2; ++i)
#pragma unroll
    for (int j = 0; j < 4; ++j) acc[i][j] = z4;

  for (int k0 = 0; k0 < K; k0 += 64) {
    __syncthreads();
#pragma unroll
    for (int t = 0; t < 4; ++t) {                  // A: 1024 chunks
      const int cbase = wave * 64 + t * 256;
      const int L   = cbase + lane;
      const int row = L >> 3;
      const int h8  = (L - row) & 7;
      async16(A + (size_t)(row0 + row) * K + k0 + h8 * 8, As + cbase * 8);
    }
#pragma unroll
    for (int t = 0; t < 2; ++t) {                  // B: 512 chunks
      const int cbase = wave * 64 + t * 256;
      const int L   = cbase + lane;
      const int row = L >> 3;
      const int h8  = (L - row) & 7;
      async16(W + (size_t)(col0 + row) * K + k0 + h8 * 8, Bs + cbase * 8);
    }
    __syncthreads();

#pragma unroll
    for (int ks = 0; ks < 2; ++ks) {
      const int c = ks * 4 + quad;
      bf16x8 af[2], bfr[4];
#pragma unroll
      for (int i = 0; i < 2; ++i) {
        const int m = wm + i * 16 + l16;
        af[i] = *(const bf16x8_a*)(As + m * 64 + ((c + m) & 7) * 8);
      }
#pragma unroll
      for (int j = 0; j < 4; ++j) {
        const int n = j * 16 + l16;
        bfr[j] = *(const bf16x8_a*)(Bs + n * 64 + ((c + n) & 7) * 8);
      }
#pragma unroll
      for (int i = 0; i < 2; ++i)
#pragma unroll
        for (int j = 0; j < 4; ++j)
          acc[i][j] = __builtin_amdgcn_mfma_f32_16x16x32_bf16(af[i], bfr[j], acc[i][j], 0, 0, 0);
    }
  }

#pragma unroll
  for (int j = 0; j < 4; ++j) {
    const int n = col0 + j * 16 + l16;
    const float bn = bias[n];
#pragma unroll
    for (int i = 0; i < 2; ++i)
#pragma unroll
      for (int r = 0; r < 4; ++r) {
        const int m = row0 + wm + i * 16 + quad * 4 + r;
        C[(size_t)m * ND + n] = acc[i][j][r] + bn;
      }
  }
}

// ---------------- Flash attention v8: v7 + KT=128 (2 sub-tiles per barrier) -----------
// 512-thr blocks: 8 waves x 32 q-rows = 256 q/block; grid (32,8) = 256 blocks = 1/CU.
// LDS 64 KiB: double-buffered 128-key K tile + V tile (2 sub-tiles). 16 iterations,
// ONE barrier + one DMA-drain per 128 keys (v7 paid that per 64 keys — the measured
// per-iter overhead ~1000cyc was the residual wall). The two 64-key sub-tiles are
// independent until the o-accumulate, so sh=1 ds_reads/MFMAs overlap sh=0's
// exp2/pack chain (free ILP). Staged bytes/key unchanged; id%8 = bh%8 keeps each
// head's K/V on one XCD's L2.
__global__ __launch_bounds__(512, 1)
void attn(const u16* __restrict__ Qb, const u16* __restrict__ Kb,
          const u16* __restrict__ Vb, u16* __restrict__ Yb) {
  __shared__ alignas(16) u16 Ks[2][128 * 64];     // [buf][key][hd] (rotation-swizzled)
  __shared__ alignas(16) u16 Vt[2][2][64 * 64];   // [buf][sub][hd][key'] (swizzled)

  const int tid  = threadIdx.x;
  const int lane = tid & 63;
  const int wave = tid >> 6;                    // 0..7
  const int l16  = lane & 15;
  const int quad = lane >> 4;

  const int bh = blockIdx.x;                    // b*NH + h
  const int q0 = blockIdx.y * 256;
  const u16* Q  = Qb + (size_t)bh * NT * NHD;
  const u16* Kg = Kb + (size_t)bh * NT * NHD;   // [key][hd]
  const u16* Vg = Vb + (size_t)bh * NHD * NT;   // [hd][tP], key-permuted per 64-block
  const int b = bh >> 4, h = bh & (NH - 1);
  u16* Y = Yb + (size_t)b * NT * ND + h * NHD;

  const int qw = q0 + wave * 32;                // 32 q-rows per wave

  // Q B-fragments (pre-scaled by SCALE_LOG2E in gemm_qkv), resident
  bf16x8 qf[2][2];                              // [q-half][ks]
#pragma unroll
  for (int n = 0; n < 2; ++n)
#pragma unroll
    for (int ks = 0; ks < 2; ++ks)
      qf[n][ks] = *(const bf16x8_a*)(Q + (size_t)(qw + n * 16 + l16) * NHD + ks * 32 + quad * 8);

  const f32x4 z4 = {0.f, 0.f, 0.f, 0.f};
  f32x4 o[2][4];
  float lacc[2] = {0.f, 0.f};
#pragma unroll
  for (int m = 0; m < 2; ++m)
#pragma unroll
    for (int n = 0; n < 4; ++n) o[m][n] = z4;

  auto stage = [&](int key0, int buf) {
    // K: 1024 chunks (128 rows), V: 2 sub-tiles x 512 chunks; 512 threads
#pragma unroll
    for (int t = 0; t < 2; ++t) {
      const int cbase = wave * 64;              // wave-uniform
      const int L   = cbase + lane;             // 0..511
      const int row = L >> 3;                   // 0..63
      const int h8  = (L - row) & 7;            // slot invariant (h8+row)&7 == L&7
      async16(Kg + (size_t)(key0 + t * 64 + row) * NHD + h8 * 8,
              &Ks[buf][0] + (t * 512 + cbase) * 8);
      async16(Vg + (size_t)row * NT + key0 + t * 64 + h8 * 8,
              &Vt[buf][t][0] + cbase * 8);
    }
  };

  stage(0, 0);
  __syncthreads();                              // drain prologue DMA

  for (int kb = 0; kb < NT / 128; ++kb) {
    const int buf = kb & 1;
    if (kb + 1 < NT / 128) stage((kb + 1) * 128, buf ^ 1);   // prefetch, in flight all iter

#pragma unroll
    for (int sh = 0; sh < 2; ++sh) {            // two 64-key sub-tiles per barrier
      // S^T = K Q^T : s[km][qn] -> key = sh*64+km*16+quad*4+r, q = qn*16+l16
      f32x4 s[4][2];
#pragma unroll
      for (int km = 0; km < 4; ++km)
#pragma unroll
        for (int qn = 0; qn < 2; ++qn) s[km][qn] = z4;
#pragma unroll
      for (int ks = 0; ks < 2; ++ks) {
        const int c = ks * 4 + quad;
        bf16x8 kf[4];
#pragma unroll
        for (int km = 0; km < 4; ++km) {
          const int key = km * 16 + l16;
          kf[km] = *(const bf16x8_a*)(&Ks[buf][0] + (sh * 64 + key) * 64 + ((c + key) & 7) * 8);
        }
#pragma unroll
        for (int km = 0; km < 4; ++km)
#pragma unroll
          for (int qn = 0; qn < 2; ++qn)
            s[km][qn] = __builtin_amdgcn_mfma_f32_16x16x32_bf16(kf[km], qf[qn][ks], s[km][qn], 0, 0, 0);
      }

      // softmax (scores pre-scaled): p = 2^s; per-lane partial row sums
#pragma unroll
      for (int qn = 0; qn < 2; ++qn) {
        float rs = 0.f;
#pragma unroll
        for (int km = 0; km < 4; ++km)
#pragma unroll
          for (int r = 0; r < 4; ++r) {
            const float p = __builtin_amdgcn_exp2f(s[km][qn][r]);
            s[km][qn][r] = p;
            rs += p;
          }
        lacc[qn] += rs;
      }

      // O += P V ; pf[qm][ks] element e = P[q][32ks+16(e>>2)+4quad+(e&3)] (in registers)
#pragma unroll
      for (int ks = 0; ks < 2; ++ks) {
        const int c = ks * 4 + quad;
        bf16x8 vf[4];
#pragma unroll
        for (int hn = 0; hn < 4; ++hn) {
          const int hd = hn * 16 + l16;
          vf[hn] = *(const bf16x8_a*)(&Vt[buf][sh][0] + hd * 64 + ((c + hd) & 7) * 8);
        }
#pragma unroll
        for (int qm = 0; qm < 2; ++qm) {
          u32x4 pwv;
          pwv[0] = pack2_tr(s[2 * ks][qm][0],     s[2 * ks][qm][1]);
          pwv[1] = pack2_tr(s[2 * ks][qm][2],     s[2 * ks][qm][3]);
          pwv[2] = pack2_tr(s[2 * ks + 1][qm][0], s[2 * ks + 1][qm][1]);
          pwv[3] = pack2_tr(s[2 * ks + 1][qm][2], s[2 * ks + 1][qm][3]);
          const bf16x8 pf = __builtin_bit_cast(bf16x8, pwv);
#pragma unroll
          for (int hn = 0; hn < 4; ++hn)
            o[qm][hn] = __builtin_amdgcn_mfma_f32_16x16x32_bf16(pf, vf[hn], o[qm][hn], 0, 0, 0);
        }
      }
    }

    __syncthreads();   // drains prefetch DMA (overlapped with compute) + buf protection
  }

  // epilogue: reduce l across quads (q lives at l16), redistribute, O/l -> Y
#pragma unroll
  for (int qm = 0; qm < 2; ++qm) {
    float l = lacc[qm];
    l += __shfl_xor(l, 16);
    l += __shfl_xor(l, 32);
#pragma unroll
    for (int r = 0; r < 4; ++r) {
      const float inv = 1.0f / __shfl(l, quad * 4 + r);
      const int t = qw + qm * 16 + quad * 4 + r;
#pragma unroll
      for (int hn = 0; hn < 4; ++hn)
        Y[(size_t)t * ND + hn * 16 + l16] = f2b(o[qm][hn][r] * inv);
    }
  }
}

extern "C" void kernel_launch(void* const* d_in, const int* in_sizes, int n_in,
                              void* d_out, int out_size, void* d_ws, size_t ws_size,
                              hipStream_t stream) {
  // inputs fp32, output fp32 (round-6-verified).
  const float* x     = (const float*)d_in[0];
  const float* w_qkv = (const float*)d_in[2];
  const float* b_qkv = (const float*)d_in[3];
  const float* w_out = (const float*)d_in[4];
  const float* b_out = (const float*)d_in[5];

  u16* ws = (u16*)d_ws;
  const size_t perbuf = (size_t)NB * NH * NT * NHD;  // 4,194,304 elems
  u16* qkv   = ws;                                   // [0,24MB): Q|K|V^T (bf16)
  u16* xb    = ws + 3 * perbuf;                      // [24,32MB): x bf16, reused as y
  u16* y     = xb;
  u16* wqkvb = ws + 4 * perbuf;                      // [32,38MB): w_qkv bf16
  u16* woutb = wqkvb + (size_t)3 * ND * ND;          // [38,40MB): w_out bf16

  cvt_all<<<dim3(4096), dim3(256), 0, stream>>>(x, w_qkv, w_out, xb, wqkvb, woutb);
  gemm_qkv<<<dim3(32, 24), dim3(256), 0, stream>>>(xb, wqkvb, b_qkv, qkv);
  attn<<<dim3(32, 8), dim3(512), 0, stream>>>(qkv, qkv + perbuf, qkv + 2 * perbuf, y);
  gemm_out<<<dim3(32, 16), dim3(256), 0, stream>>>(y, woutb, b_out, (float*)d_out);
}